// Round 10
// baseline (657.545 us; speedup 1.0000x reference)
//
#include <hip/hip_runtime.h>
#include <hip/hip_cooperative_groups.h>
#include <math.h>

namespace cg = cooperative_groups;

#define BATCH 128

typedef __attribute__((ext_vector_type(8))) short bf16x8;
typedef __attribute__((ext_vector_type(4))) float f32x4;

__device__ __forceinline__ unsigned short f2bf(float f) {
    unsigned u = __builtin_bit_cast(unsigned, f);
    u += 0x7FFF + ((u >> 16) & 1);          // RNE
    return (unsigned short)(u >> 16);
}
__device__ __forceinline__ float bf2f(unsigned short h) {
    unsigned u = ((unsigned)h) << 16;
    return __builtin_bit_cast(float, u);
}

struct KParams {
    const float* x;
    const float* W[11];
    const float* B[11];
    const int*   S[11];
    const float* fcW;
    const float* fcb;
    float*       out;
    unsigned short* buf0;
    unsigned short* buf1;
    unsigned short* Wb;
};

// ============================================================================
// MFMA layer phase (verified R9 body, task-strided).
// Xin [2*NP][128][CIN] bf16, Wb [3*CF][CIN] bf16 -> Xout [NP][128][CF] bf16.
// A frag: W[f0+mi*16+c][q*8+k..]; B frag: X[2n+p][b0+ni*16+c][q*8+k..]
// D: col(b)=lane&15, row(f)=q*4+reg.
// ============================================================================
template<int CIN, int CF, int NP, int MW, int NW>
__device__ void mfma_layer(int gwave, int lane,
    const unsigned short* __restrict__ Xin,
    const unsigned short* __restrict__ Wb,
    const float* __restrict__ bias,
    const int*   __restrict__ sel,
    unsigned short* __restrict__ Xout)
{
    constexpr int FT = CF / (16 * MW);
    constexpr int BT = 128 / (16 * NW);
    constexpr int TASKS = NP * FT * BT;

    const int c = lane & 15;
    const int q = lane >> 4;

    for (int task = gwave; task < TASKS; task += 2048) {
        const int bi = task % BT;
        const int fi = (task / BT) % FT;
        const int n  = task / (BT * FT);

        const int s0 = __builtin_amdgcn_readfirstlane(sel[2 * n]);
        const int s1 = __builtin_amdgcn_readfirstlane(sel[2 * n + 1]);

        const int f0 = fi * 16 * MW;
        const int b0 = bi * 16 * NW;

        const unsigned short* ap[2][MW];
        const unsigned short* bp[2][NW];
#pragma unroll
        for (int p = 0; p < 2; ++p) {
            int s = p ? s1 : s0;
#pragma unroll
            for (int mi = 0; mi < MW; ++mi)
                ap[p][mi] = Wb + (size_t)((f0 + mi * 16 + c) * 3 + s) * CIN + q * 8;
#pragma unroll
            for (int ni = 0; ni < NW; ++ni)
                bp[p][ni] = Xin + ((size_t)(2 * n + p) * 128 + b0 + ni * 16 + c) * CIN + q * 8;
        }

        f32x4 acc[2][MW][NW];
#pragma unroll
        for (int p = 0; p < 2; ++p)
#pragma unroll
            for (int mi = 0; mi < MW; ++mi)
#pragma unroll
                for (int ni = 0; ni < NW; ++ni)
                    acc[p][mi][ni] = (f32x4){0.f, 0.f, 0.f, 0.f};

#pragma unroll 2
        for (int k = 0; k < CIN; k += 32) {
            bf16x8 A[2][MW], B[2][NW];
#pragma unroll
            for (int p = 0; p < 2; ++p) {
#pragma unroll
                for (int mi = 0; mi < MW; ++mi)
                    A[p][mi] = __builtin_bit_cast(bf16x8, *(const float4*)(const void*)(ap[p][mi] + k));
#pragma unroll
                for (int ni = 0; ni < NW; ++ni)
                    B[p][ni] = __builtin_bit_cast(bf16x8, *(const float4*)(const void*)(bp[p][ni] + k));
            }
#pragma unroll
            for (int p = 0; p < 2; ++p)
#pragma unroll
                for (int mi = 0; mi < MW; ++mi)
#pragma unroll
                    for (int ni = 0; ni < NW; ++ni)
                        acc[p][mi][ni] = __builtin_amdgcn_mfma_f32_16x16x32_bf16(
                            A[p][mi], B[p][ni], acc[p][mi][ni], 0, 0, 0);
        }

#pragma unroll
        for (int mi = 0; mi < MW; ++mi) {
            int fbase = f0 + mi * 16 + q * 4;
            float bi0[4], bi1[4];
#pragma unroll
            for (int r = 0; r < 4; ++r) {
                bi0[r] = bias[(fbase + r) * 3 + s0];
                bi1[r] = bias[(fbase + r) * 3 + s1];
            }
#pragma unroll
            for (int ni = 0; ni < NW; ++ni) {
                int b = b0 + ni * 16 + c;
                unsigned short o[4];
#pragma unroll
                for (int r = 0; r < 4; ++r) {
                    float v = fmaxf(fmaxf(acc[0][mi][ni][r] + bi0[r],
                                          acc[1][mi][ni][r] + bi1[r]), 0.f);
                    o[r] = f2bf(v);
                }
                *(ushort4*)(Xout + ((size_t)n * 128 + b) * CF + fbase) =
                    make_ushort4(o[0], o[1], o[2], o[3]);
            }
        }
    }
}

// ============================================================================
// Mega-kernel: 256 blocks x 512 threads, 13 phases with grid.sync().
// ============================================================================
__global__ __launch_bounds__(512) void mega_kernel(KParams P)
{
    cg::grid_group grid = cg::this_grid();
    constexpr int NT = 256 * 512;
    const int tid     = threadIdx.x;
    const int gthread = blockIdx.x * 512 + tid;
    const int gwave   = gthread >> 6;
    const int lane    = tid & 63;

    __shared__ float swl[768];
    __shared__ float sbl[96];

    // ---- phase 0: pack W3..W11 fp32 -> bf16 (original [3*cf][cin] layout) ----
    {
        constexpr int we[9] = {6144, 12288, 12288, 24576, 98304, 393216, 786432, 786432, 1572864};
        int off = 0;
#pragma unroll
        for (int li = 0; li < 9; ++li) {
            const float4* src = (const float4*)P.W[li + 2];
            ushort4* dst = (ushort4*)(P.Wb + off);
            int n4 = we[li] >> 2;
            for (int i = gthread; i < n4; i += NT) {
                float4 w = src[i];
                dst[i] = make_ushort4(f2bf(w.x), f2bf(w.y), f2bf(w.z), f2bf(w.w));
            }
            off += we[li];
        }
    }
    // stage L1 weights to LDS (consumed next phase)
    if (tid < 72) swl[tid] = P.W[0][tid];
    if (tid >= 128 && tid < 152) sbl[tid - 128] = P.B[0][tid - 128];
    grid.sync();

    // ---- phase 1: L1  x [128][3][2048] -> buf0 [1024][128][8] bf16 ----
    {
        int t  = gthread;                 // exactly 131072 work items
        int np = t & 1023;
        int b  = t >> 10;
        int s0 = P.S[0][2 * np], s1 = P.S[0][2 * np + 1];

        const float* xb = P.x + (size_t)b * 6144 + 2 * np;
        float2 c0 = *(const float2*)(xb);
        float2 c1 = *(const float2*)(xb + 2048);
        float2 c2 = *(const float2*)(xb + 4096);

        unsigned short o[8];
#pragma unroll
        for (int f = 0; f < 8; ++f) {
            int r0 = f * 3 + s0, r1 = f * 3 + s1;
            float z0 = fmaf(swl[r0*3+2], c2.x, fmaf(swl[r0*3+1], c1.x, fmaf(swl[r0*3+0], c0.x, sbl[r0])));
            float z1 = fmaf(swl[r1*3+2], c2.y, fmaf(swl[r1*3+1], c1.y, fmaf(swl[r1*3+0], c0.y, sbl[r1])));
            o[f] = f2bf(fmaxf(fmaxf(z0, z1), 0.f));
        }
        unsigned short* dst = P.buf0 + ((size_t)np * 128 + b) * 8;
        *(ushort4*)dst       = make_ushort4(o[0], o[1], o[2], o[3]);
        *(ushort4*)(dst + 4) = make_ushort4(o[4], o[5], o[6], o[7]);
    }
    grid.sync();

    // stage L2 weights to LDS
    for (int i = tid; i < 768; i += 512) swl[i] = P.W[1][i];
    if (tid < 96) sbl[tid] = P.B[1][tid];
    __syncthreads();

    // ---- phase 2: L2  buf0 -> buf1 [512][128][32] bf16 ----
    if (gthread < 65536) {
        int t  = gthread;
        int b  = t & 127;
        int np = t >> 7;
        int s0 = P.S[1][2 * np], s1 = P.S[1][2 * np + 1];

        const unsigned short* r0 = P.buf0 + ((size_t)(2 * np) * 128 + b) * 8;
        const unsigned short* r1 = P.buf0 + ((size_t)(2 * np + 1) * 128 + b) * 8;
        float xa[8], xb[8];
        {
            ushort4 u0 = *(const ushort4*)r0, u1 = *(const ushort4*)(r0 + 4);
            ushort4 v0 = *(const ushort4*)r1, v1 = *(const ushort4*)(r1 + 4);
            xa[0]=bf2f(u0.x); xa[1]=bf2f(u0.y); xa[2]=bf2f(u0.z); xa[3]=bf2f(u0.w);
            xa[4]=bf2f(u1.x); xa[5]=bf2f(u1.y); xa[6]=bf2f(u1.z); xa[7]=bf2f(u1.w);
            xb[0]=bf2f(v0.x); xb[1]=bf2f(v0.y); xb[2]=bf2f(v0.z); xb[3]=bf2f(v0.w);
            xb[4]=bf2f(v1.x); xb[5]=bf2f(v1.y); xb[6]=bf2f(v1.z); xb[7]=bf2f(v1.w);
        }
        unsigned short o[32];
#pragma unroll
        for (int f = 0; f < 32; ++f) {
            const float* w0 = &swl[(f * 3 + s0) * 8];
            const float* w1 = &swl[(f * 3 + s1) * 8];
            float z0 = sbl[f * 3 + s0], z1 = sbl[f * 3 + s1];
#pragma unroll
            for (int k = 0; k < 8; ++k) {
                z0 = fmaf(w0[k], xa[k], z0);
                z1 = fmaf(w1[k], xb[k], z1);
            }
            o[f] = f2bf(fmaxf(fmaxf(z0, z1), 0.f));
        }
        unsigned short* dst = P.buf1 + ((size_t)np * 128 + b) * 32;
#pragma unroll
        for (int i = 0; i < 8; ++i)
            *(ushort4*)(dst + 4 * i) = make_ushort4(o[4*i], o[4*i+1], o[4*i+2], o[4*i+3]);
    }
    grid.sync();

    // ---- phases 3..11: MFMA layers (Wb offsets precomputed) ----
    mfma_layer<32, 64, 256, 2, 2>(gwave, lane, P.buf1, P.Wb + 0,       P.B[2],  P.S[2],  P.buf0);
    grid.sync();
    mfma_layer<64, 64, 128, 2, 2>(gwave, lane, P.buf0, P.Wb + 6144,    P.B[3],  P.S[3],  P.buf1);
    grid.sync();
    mfma_layer<64, 64, 64, 2, 2>(gwave, lane, P.buf1, P.Wb + 18432,    P.B[4],  P.S[4],  P.buf0);
    grid.sync();
    mfma_layer<64, 128, 32, 2, 2>(gwave, lane, P.buf0, P.Wb + 30720,   P.B[5],  P.S[5],  P.buf1);
    grid.sync();
    mfma_layer<128, 256, 16, 2, 2>(gwave, lane, P.buf1, P.Wb + 55296,  P.B[6],  P.S[6],  P.buf0);
    grid.sync();
    mfma_layer<256, 512, 8, 2, 2>(gwave, lane, P.buf0, P.Wb + 153600,  P.B[7],  P.S[7],  P.buf1);
    grid.sync();
    mfma_layer<512, 512, 4, 1, 2>(gwave, lane, P.buf1, P.Wb + 546816,  P.B[8],  P.S[8],  P.buf0);
    grid.sync();
    mfma_layer<512, 512, 2, 1, 2>(gwave, lane, P.buf0, P.Wb + 1333248, P.B[9],  P.S[9],  P.buf1);
    grid.sync();
    mfma_layer<512, 1024, 1, 1, 2>(gwave, lane, P.buf1, P.Wb + 2119680, P.B[10], P.S[10], P.buf0);
    grid.sync();

    // ---- phase 12: FC + log-softmax.  h = buf0 [128][1024] bf16 ----
    if (gwave < 128) {
        int b = gwave;
        int k = lane & 15;
        int q = lane >> 4;
        const unsigned short* hq = P.buf0 + (size_t)b * 1024 + q * 256;
        const float* wq = P.fcW + (size_t)k * 1024 + q * 256;

        float partial = 0.f;
#pragma unroll 8
        for (int j = 0; j < 256; j += 4) {
            ushort4 h4 = *(const ushort4*)(hq + j);
            float4  w4 = *(const float4*)(wq + j);
            partial = fmaf(bf2f(h4.x), w4.x, partial);
            partial = fmaf(bf2f(h4.y), w4.y, partial);
            partial = fmaf(bf2f(h4.z), w4.z, partial);
            partial = fmaf(bf2f(h4.w), w4.w, partial);
        }
        partial += __shfl_xor(partial, 16, 64);
        partial += __shfl_xor(partial, 32, 64);
        float logit = partial + P.fcb[k];

        float m = logit;
#pragma unroll
        for (int off = 1; off < 16; off <<= 1) m = fmaxf(m, __shfl_xor(m, off, 16));
        float se = expf(logit - m);
#pragma unroll
        for (int off = 1; off < 16; off <<= 1) se += __shfl_xor(se, off, 16);

        if (lane < 16) P.out[b * 16 + k] = logit - m - logf(se);
    }
}

// ============================================================================
extern "C" void kernel_launch(void* const* d_in, const int* in_sizes, int n_in,
                              void* d_out, int out_size, void* d_ws, size_t ws_size,
                              hipStream_t stream)
{
    KParams P;
    P.x = (const float*)d_in[0];
    for (int i = 0; i < 11; ++i) {
        P.W[i] = (const float*)d_in[1 + 3 * i];
        P.B[i] = (const float*)d_in[2 + 3 * i];
        P.S[i] = (const int*)  d_in[3 + 3 * i];
    }
    P.fcW = (const float*)d_in[34];
    P.fcb = (const float*)d_in[35];
    P.out = (float*)d_out;

    unsigned short* buf0 = (unsigned short*)d_ws;          // 4 MB
    unsigned short* buf1 = buf0 + 2u * 1024u * 1024u;      // 4 MB
    unsigned short* Wb   = buf1 + 2u * 1024u * 1024u;      // packed bf16 W (7.4 MB)
    P.buf0 = buf0; P.buf1 = buf1; P.Wb = Wb;

    void* args[] = { &P };
    hipLaunchCooperativeKernel((const void*)mega_kernel,
                               dim3(256), dim3(512), args, 0, stream);
}

// Round 11
// 237.382 us; speedup vs baseline: 2.7700x; 2.7700x over previous
//
#include <hip/hip_runtime.h>
#include <math.h>

typedef __attribute__((ext_vector_type(8))) short bf16x8;
typedef __attribute__((ext_vector_type(4))) float f32x4;

__device__ __forceinline__ unsigned short f2bf(float f) {
    unsigned u = __builtin_bit_cast(unsigned, f);
    u += 0x7FFF + ((u >> 16) & 1);          // RNE
    return (unsigned short)(u >> 16);
}
__device__ __forceinline__ float bf2f(unsigned short h) {
    unsigned u = ((unsigned)h) << 16;
    return __builtin_bit_cast(float, u);
}

// ============================================================================
// K1: [blocks 0..127]  L1+L2 fused via LDS  |  [blocks 128..191] pack W6..W11
// L1: x [128][3][2048] fp32 -> LDS [16pos][64b][8f] bf16
// L2: LDS -> X3 [512][128][32] bf16
// ============================================================================
struct K1Params {
    const float* x;
    const float* W1; const float* B1; const int* S1;
    const float* W2; const float* B2; const int* S2;
    const float* Wsrc[6];          // W6..W11 fp32
    unsigned short* Wb;            // packed bf16 out
    unsigned short* X3;
};

__global__ __launch_bounds__(256) void k1_kernel(K1Params P)
{
    const int tid = threadIdx.x;

    if (blockIdx.x >= 128) {
        // ---- pack W6..W11 fp32 -> bf16 ----
        int gt = (blockIdx.x - 128) * 256 + tid;    // 0..16383
        const int we[6] = {24576, 98304, 393216, 786432, 786432, 1572864};
        int off = 0;
#pragma unroll
        for (int li = 0; li < 6; ++li) {
            const float4* src = (const float4*)P.Wsrc[li];
            ushort4* dst = (ushort4*)(P.Wb + off);
            int n4 = we[li] >> 2;
            for (int i = gt; i < n4; i += 16384) {
                float4 w = src[i];
                dst[i] = make_ushort4(f2bf(w.x), f2bf(w.y), f2bf(w.z), f2bf(w.w));
            }
            off += we[li];
        }
        return;
    }

    __shared__ float wl1[72], bl1[24], wl2[768], bl2[96];
    __shared__ unsigned short bufL1[16 * 64 * 8];

    if (tid < 72) wl1[tid] = P.W1[tid];
    if (tid >= 128 && tid < 152) bl1[tid - 128] = P.B1[tid - 128];
    for (int i = tid; i < 768; i += 256) wl2[i] = P.W2[i];
    if (tid < 96) bl2[tid] = P.B2[tid];
    __syncthreads();

    const int npT = blockIdx.x >> 1;          // 0..63: L2-out positions [npT*8, +8)
    const int b0  = (blockIdx.x & 1) * 64;

    // ---- L1: 16 L1-out positions x 64 b ----
    for (int i = tid; i < 1024; i += 256) {
        int pos_l = i >> 6, bl = i & 63;
        int np1 = npT * 16 + pos_l;
        int b = b0 + bl;
        int s0 = P.S1[2 * np1], s1 = P.S1[2 * np1 + 1];
        const float* xb = P.x + (size_t)b * 6144 + 2 * np1;
        float2 c0 = *(const float2*)(xb);
        float2 c1 = *(const float2*)(xb + 2048);
        float2 c2 = *(const float2*)(xb + 4096);
        unsigned short o[8];
#pragma unroll
        for (int f = 0; f < 8; ++f) {
            int r0 = f * 3 + s0, r1 = f * 3 + s1;
            float z0 = fmaf(wl1[r0*3+2], c2.x, fmaf(wl1[r0*3+1], c1.x, fmaf(wl1[r0*3+0], c0.x, bl1[r0])));
            float z1 = fmaf(wl1[r1*3+2], c2.y, fmaf(wl1[r1*3+1], c1.y, fmaf(wl1[r1*3+0], c0.y, bl1[r1])));
            o[f] = f2bf(fmaxf(fmaxf(z0, z1), 0.f));
        }
        unsigned short* dst = &bufL1[((size_t)pos_l * 64 + bl) * 8];
        *(ushort4*)dst       = make_ushort4(o[0], o[1], o[2], o[3]);
        *(ushort4*)(dst + 4) = make_ushort4(o[4], o[5], o[6], o[7]);
    }
    __syncthreads();

    // ---- L2: 8 L2-out positions x 64 b ----
    for (int i = tid; i < 512; i += 256) {
        int np_l = i >> 6, bl = i & 63;
        int np2 = npT * 8 + np_l;
        int s0 = P.S2[2 * np2], s1 = P.S2[2 * np2 + 1];
        const unsigned short* r0 = &bufL1[((size_t)(2 * np_l) * 64 + bl) * 8];
        const unsigned short* r1 = &bufL1[((size_t)(2 * np_l + 1) * 64 + bl) * 8];
        float xa[8], xb[8];
        {
            ushort4 u0 = *(const ushort4*)r0, u1 = *(const ushort4*)(r0 + 4);
            ushort4 v0 = *(const ushort4*)r1, v1 = *(const ushort4*)(r1 + 4);
            xa[0]=bf2f(u0.x); xa[1]=bf2f(u0.y); xa[2]=bf2f(u0.z); xa[3]=bf2f(u0.w);
            xa[4]=bf2f(u1.x); xa[5]=bf2f(u1.y); xa[6]=bf2f(u1.z); xa[7]=bf2f(u1.w);
            xb[0]=bf2f(v0.x); xb[1]=bf2f(v0.y); xb[2]=bf2f(v0.z); xb[3]=bf2f(v0.w);
            xb[4]=bf2f(v1.x); xb[5]=bf2f(v1.y); xb[6]=bf2f(v1.z); xb[7]=bf2f(v1.w);
        }
        unsigned short o[32];
#pragma unroll
        for (int f = 0; f < 32; ++f) {
            const float* w0 = &wl2[(f * 3 + s0) * 8];
            const float* w1 = &wl2[(f * 3 + s1) * 8];
            float z0 = bl2[f * 3 + s0], z1 = bl2[f * 3 + s1];
#pragma unroll
            for (int k = 0; k < 8; ++k) {
                z0 = fmaf(w0[k], xa[k], z0);
                z1 = fmaf(w1[k], xb[k], z1);
            }
            o[f] = f2bf(fmaxf(fmaxf(z0, z1), 0.f));
        }
        unsigned short* dst = P.X3 + ((size_t)np2 * 128 + b0 + bl) * 32;
#pragma unroll
        for (int i2 = 0; i2 < 8; ++i2)
            *(ushort4*)(dst + 4 * i2) = make_ushort4(o[4*i2], o[4*i2+1], o[4*i2+2], o[4*i2+3]);
    }
}

// ============================================================================
// MFMA tile helper: 16x16x32_bf16 over K=CIN for both pool positions.
// a0/a1: A-frag base (row (f0+c)*3+s applied, +q*8), stride along k.
// b0p/b1p: B-frag base for pos0/pos1 (+q*8).
// ============================================================================
template<int CIN>
__device__ __forceinline__ void mfma_tile(
    const unsigned short* a0, const unsigned short* a1,
    const unsigned short* b0p, const unsigned short* b1p,
    f32x4& acc0, f32x4& acc1)
{
#pragma unroll
    for (int k = 0; k < CIN; k += 32) {
        bf16x8 A0 = __builtin_bit_cast(bf16x8, *(const float4*)(const void*)(a0 + k));
        bf16x8 A1 = __builtin_bit_cast(bf16x8, *(const float4*)(const void*)(a1 + k));
        bf16x8 B0 = __builtin_bit_cast(bf16x8, *(const float4*)(const void*)(b0p + k));
        bf16x8 B1 = __builtin_bit_cast(bf16x8, *(const float4*)(const void*)(b1p + k));
        acc0 = __builtin_amdgcn_mfma_f32_16x16x32_bf16(A0, B0, acc0, 0, 0, 0);
        acc1 = __builtin_amdgcn_mfma_f32_16x16x32_bf16(A1, B1, acc1, 0, 0, 0);
    }
}

__device__ __forceinline__ void epilogue_store(
    unsigned short* dst, const f32x4& acc0, const f32x4& acc1,
    const float* bias, int fbase, int s0, int s1)
{
    unsigned short o[4];
#pragma unroll
    for (int r = 0; r < 4; ++r) {
        float v = fmaxf(fmaxf(acc0[r] + bias[(fbase + r) * 3 + s0],
                              acc1[r] + bias[(fbase + r) * 3 + s1]), 0.f);
        o[r] = f2bf(v);
    }
    *(ushort4*)dst = make_ushort4(o[0], o[1], o[2], o[3]);
}

// ============================================================================
// K2: L3+L4+L5 fused. Block = (n5 of 64, bq of 4 -> b-tile 32). 256 blocks.
// W3..W5 cvt'd fp32->bf16 into LDS once; intermediates in LDS [pos][b][ch].
// X3 [512][128][32] -> X6 [64][128][64]
// ============================================================================
__global__ __launch_bounds__(256) void stage2_kernel(
    const unsigned short* __restrict__ X3,
    const float* __restrict__ W3f, const float* __restrict__ B3, const int* __restrict__ S3,
    const float* __restrict__ W4f, const float* __restrict__ B4, const int* __restrict__ S4,
    const float* __restrict__ W5f, const float* __restrict__ B5, const int* __restrict__ S5,
    unsigned short* __restrict__ X6)
{
    __shared__ unsigned short W3l[6144];       // [192][32]
    __shared__ unsigned short W4l[12288];      // [192][64]
    __shared__ unsigned short W5l[12288];      // [192][64]
    __shared__ unsigned short L3o[4 * 32 * 64];  // [j][bl][ch]
    __shared__ unsigned short L4o[2 * 32 * 64];

    const int tid  = threadIdx.x;
    const int lane = tid & 63;
    const int wv   = tid >> 6;
    const int c = lane & 15, q = lane >> 4;
    const int n5 = blockIdx.x >> 2;
    const int b0 = (blockIdx.x & 3) * 32;

    // ---- cvt W3..W5 to LDS ----
    for (int i = tid; i < 1536; i += 256) {
        float4 w = ((const float4*)W3f)[i];
        ((ushort4*)W3l)[i] = make_ushort4(f2bf(w.x), f2bf(w.y), f2bf(w.z), f2bf(w.w));
    }
    for (int i = tid; i < 3072; i += 256) {
        float4 w = ((const float4*)W4f)[i];
        ((ushort4*)W4l)[i] = make_ushort4(f2bf(w.x), f2bf(w.y), f2bf(w.z), f2bf(w.w));
        float4 v = ((const float4*)W5f)[i];
        ((ushort4*)W5l)[i] = make_ushort4(f2bf(v.x), f2bf(v.y), f2bf(v.z), f2bf(v.w));
    }
    __syncthreads();

    // ---- L3 (CIN=32): out local j=0..3 (global pos 4n5+j), in X3 global ----
    for (int t = wv; t < 32; t += 4) {
        int bt = t & 1, ft = (t >> 1) & 3, j = t >> 3;
        int np = 4 * n5 + j;
        int s0 = __builtin_amdgcn_readfirstlane(S3[2 * np]);
        int s1 = __builtin_amdgcn_readfirstlane(S3[2 * np + 1]);
        int f0 = ft * 16, bl = bt * 16;
        const unsigned short* a0 = &W3l[((f0 + c) * 3 + s0) * 32 + q * 8];
        const unsigned short* a1 = &W3l[((f0 + c) * 3 + s1) * 32 + q * 8];
        const unsigned short* bp0 = X3 + ((size_t)(8 * n5 + 2 * j) * 128 + b0 + bl + c) * 32 + q * 8;
        const unsigned short* bp1 = X3 + ((size_t)(8 * n5 + 2 * j + 1) * 128 + b0 + bl + c) * 32 + q * 8;
        f32x4 acc0 = {0.f,0.f,0.f,0.f}, acc1 = {0.f,0.f,0.f,0.f};
        mfma_tile<32>(a0, a1, bp0, bp1, acc0, acc1);
        epilogue_store(&L3o[((size_t)j * 32 + bl + c) * 64 + f0 + q * 4],
                       acc0, acc1, B3, f0 + q * 4, s0, s1);
    }
    __syncthreads();

    // ---- L4 (CIN=64): out local j=0..1 (global pos 2n5+j), in L3o ----
    for (int t = wv; t < 16; t += 4) {
        int bt = t & 1, ft = (t >> 1) & 3, j = t >> 3;
        int np = 2 * n5 + j;
        int s0 = __builtin_amdgcn_readfirstlane(S4[2 * np]);
        int s1 = __builtin_amdgcn_readfirstlane(S4[2 * np + 1]);
        int f0 = ft * 16, bl = bt * 16;
        const unsigned short* a0 = &W4l[((f0 + c) * 3 + s0) * 64 + q * 8];
        const unsigned short* a1 = &W4l[((f0 + c) * 3 + s1) * 64 + q * 8];
        const unsigned short* bp0 = &L3o[((size_t)(2 * j) * 32 + bl + c) * 64 + q * 8];
        const unsigned short* bp1 = &L3o[((size_t)(2 * j + 1) * 32 + bl + c) * 64 + q * 8];
        f32x4 acc0 = {0.f,0.f,0.f,0.f}, acc1 = {0.f,0.f,0.f,0.f};
        mfma_tile<64>(a0, a1, bp0, bp1, acc0, acc1);
        epilogue_store(&L4o[((size_t)j * 32 + bl + c) * 64 + f0 + q * 4],
                       acc0, acc1, B4, f0 + q * 4, s0, s1);
    }
    __syncthreads();

    // ---- L5 (CIN=64): out pos n5, in L4o -> global X6 ----
    for (int t = wv; t < 8; t += 4) {
        int bt = t & 1, ft = t >> 1;
        int s0 = __builtin_amdgcn_readfirstlane(S5[2 * n5]);
        int s1 = __builtin_amdgcn_readfirstlane(S5[2 * n5 + 1]);
        int f0 = ft * 16, bl = bt * 16;
        const unsigned short* a0 = &W5l[((f0 + c) * 3 + s0) * 64 + q * 8];
        const unsigned short* a1 = &W5l[((f0 + c) * 3 + s1) * 64 + q * 8];
        const unsigned short* bp0 = &L4o[((size_t)(0) * 32 + bl + c) * 64 + q * 8];
        const unsigned short* bp1 = &L4o[((size_t)(1) * 32 + bl + c) * 64 + q * 8];
        f32x4 acc0 = {0.f,0.f,0.f,0.f}, acc1 = {0.f,0.f,0.f,0.f};
        mfma_tile<64>(a0, a1, bp0, bp1, acc0, acc1);
        epilogue_store(X6 + ((size_t)n5 * 128 + b0 + bl + c) * 64 + f0 + q * 4,
                       acc0, acc1, B5, f0 + q * 4, s0, s1);
    }
}

// ============================================================================
// K3: L6+L7+L8 fused. Block = (n8 of 8, bq of 8 -> b-tile 16). 64 blocks, 512 thr.
// W from packed bf16 Wb (global). X6 [64][128][64] -> X9 [8][128][512]
// ============================================================================
__global__ __launch_bounds__(512) void stage3_kernel(
    const unsigned short* __restrict__ X6,
    const unsigned short* __restrict__ W6b, const float* __restrict__ B6, const int* __restrict__ S6,
    const unsigned short* __restrict__ W7b, const float* __restrict__ B7, const int* __restrict__ S7,
    const unsigned short* __restrict__ W8b, const float* __restrict__ B8, const int* __restrict__ S8,
    unsigned short* __restrict__ X9)
{
    __shared__ unsigned short L6o[4 * 16 * 128];   // [j][bl][ch] 16 KB
    __shared__ unsigned short L7o[2 * 16 * 256];   // 16 KB

    const int tid  = threadIdx.x;
    const int lane = tid & 63;
    const int wv   = tid >> 6;                     // 8 waves
    const int c = lane & 15, q = lane >> 4;
    const int n8 = blockIdx.x >> 3;
    const int b0 = (blockIdx.x & 7) * 16;

    // ---- L6 (CIN=64, CF=128): out local j=0..3 (global pos 4n8+j), in X6 global ----
    for (int t = wv; t < 32; t += 8) {
        int ft = t & 7, j = t >> 3;
        int np = 4 * n8 + j;
        int s0 = __builtin_amdgcn_readfirstlane(S6[2 * np]);
        int s1 = __builtin_amdgcn_readfirstlane(S6[2 * np + 1]);
        int f0 = ft * 16;
        const unsigned short* a0 = W6b + (size_t)((f0 + c) * 3 + s0) * 64 + q * 8;
        const unsigned short* a1 = W6b + (size_t)((f0 + c) * 3 + s1) * 64 + q * 8;
        const unsigned short* bp0 = X6 + ((size_t)(8 * n8 + 2 * j) * 128 + b0 + c) * 64 + q * 8;
        const unsigned short* bp1 = X6 + ((size_t)(8 * n8 + 2 * j + 1) * 128 + b0 + c) * 64 + q * 8;
        f32x4 acc0 = {0.f,0.f,0.f,0.f}, acc1 = {0.f,0.f,0.f,0.f};
        mfma_tile<64>(a0, a1, bp0, bp1, acc0, acc1);
        epilogue_store(&L6o[((size_t)j * 16 + c) * 128 + f0 + q * 4],
                       acc0, acc1, B6, f0 + q * 4, s0, s1);
    }
    __syncthreads();

    // ---- L7 (CIN=128, CF=256): out local j=0..1 (global pos 2n8+j), in L6o ----
    for (int t = wv; t < 32; t += 8) {
        int ft = t & 15, j = t >> 4;
        int np = 2 * n8 + j;
        int s0 = __builtin_amdgcn_readfirstlane(S7[2 * np]);
        int s1 = __builtin_amdgcn_readfirstlane(S7[2 * np + 1]);
        int f0 = ft * 16;
        const unsigned short* a0 = W7b + (size_t)((f0 + c) * 3 + s0) * 128 + q * 8;
        const unsigned short* a1 = W7b + (size_t)((f0 + c) * 3 + s1) * 128 + q * 8;
        const unsigned short* bp0 = &L6o[((size_t)(2 * j) * 16 + c) * 128 + q * 8];
        const unsigned short* bp1 = &L6o[((size_t)(2 * j + 1) * 16 + c) * 128 + q * 8];
        f32x4 acc0 = {0.f,0.f,0.f,0.f}, acc1 = {0.f,0.f,0.f,0.f};
        mfma_tile<128>(a0, a1, bp0, bp1, acc0, acc1);
        epilogue_store(&L7o[((size_t)j * 16 + c) * 256 + f0 + q * 4],
                       acc0, acc1, B7, f0 + q * 4, s0, s1);
    }
    __syncthreads();

    // ---- L8 (CIN=256, CF=512): out pos n8, in L7o -> global X9 ----
    {
        int s0 = __builtin_amdgcn_readfirstlane(S8[2 * n8]);
        int s1 = __builtin_amdgcn_readfirstlane(S8[2 * n8 + 1]);
        for (int t = wv; t < 32; t += 8) {
            int f0 = t * 16;
            const unsigned short* a0 = W8b + (size_t)((f0 + c) * 3 + s0) * 256 + q * 8;
            const unsigned short* a1 = W8b + (size_t)((f0 + c) * 3 + s1) * 256 + q * 8;
            const unsigned short* bp0 = &L7o[((size_t)(0) * 16 + c) * 256 + q * 8];
            const unsigned short* bp1 = &L7o[((size_t)(1) * 16 + c) * 256 + q * 8];
            f32x4 acc0 = {0.f,0.f,0.f,0.f}, acc1 = {0.f,0.f,0.f,0.f};
            mfma_tile<256>(a0, a1, bp0, bp1, acc0, acc1);
            epilogue_store(X9 + ((size_t)n8 * 128 + b0 + c) * 512 + f0 + q * 4,
                           acc0, acc1, B8, f0 + q * 4, s0, s1);
        }
    }
}

// ============================================================================
// MFMA layer (L9..L11): verified R9 body.
// ============================================================================
template<int CIN, int CF, int NP, int MW, int NW>
__global__ __launch_bounds__(256) void mfma_kernel(
    const unsigned short* __restrict__ Xin,
    const unsigned short* __restrict__ Wb,
    const float* __restrict__ bias,
    const int*   __restrict__ sel,
    unsigned short* __restrict__ Xout)
{
    constexpr int FT = CF / (16 * MW);
    constexpr int BT = 128 / (16 * NW);

    const int wid  = threadIdx.x >> 6;
    const int lane = threadIdx.x & 63;
    const int task = blockIdx.x * 4 + wid;
    const int bi = task % BT;
    const int fi = (task / BT) % FT;
    const int n  = task / (BT * FT);

    const int c = lane & 15;
    const int q = lane >> 4;
    const int s0 = __builtin_amdgcn_readfirstlane(sel[2 * n]);
    const int s1 = __builtin_amdgcn_readfirstlane(sel[2 * n + 1]);

    const int f0 = fi * 16 * MW;
    const int b0 = bi * 16 * NW;

    const unsigned short* ap[2][MW];
    const unsigned short* bp[2][NW];
#pragma unroll
    for (int p = 0; p < 2; ++p) {
        int s = p ? s1 : s0;
#pragma unroll
        for (int mi = 0; mi < MW; ++mi)
            ap[p][mi] = Wb + (size_t)((f0 + mi * 16 + c) * 3 + s) * CIN + q * 8;
#pragma unroll
        for (int ni = 0; ni < NW; ++ni)
            bp[p][ni] = Xin + ((size_t)(2 * n + p) * 128 + b0 + ni * 16 + c) * CIN + q * 8;
    }

    f32x4 acc[2][MW][NW];
#pragma unroll
    for (int p = 0; p < 2; ++p)
#pragma unroll
        for (int mi = 0; mi < MW; ++mi)
#pragma unroll
            for (int ni = 0; ni < NW; ++ni)
                acc[p][mi][ni] = (f32x4){0.f, 0.f, 0.f, 0.f};

#pragma unroll 2
    for (int k = 0; k < CIN; k += 32) {
        bf16x8 A[2][MW], B[2][NW];
#pragma unroll
        for (int p = 0; p < 2; ++p) {
#pragma unroll
            for (int mi = 0; mi < MW; ++mi)
                A[p][mi] = __builtin_bit_cast(bf16x8, *(const float4*)(const void*)(ap[p][mi] + k));
#pragma unroll
            for (int ni = 0; ni < NW; ++ni)
                B[p][ni] = __builtin_bit_cast(bf16x8, *(const float4*)(const void*)(bp[p][ni] + k));
        }
#pragma unroll
        for (int p = 0; p < 2; ++p)
#pragma unroll
            for (int mi = 0; mi < MW; ++mi)
#pragma unroll
                for (int ni = 0; ni < NW; ++ni)
                    acc[p][mi][ni] = __builtin_amdgcn_mfma_f32_16x16x32_bf16(
                        A[p][mi], B[p][ni], acc[p][mi][ni], 0, 0, 0);
    }

#pragma unroll
    for (int mi = 0; mi < MW; ++mi) {
        int fbase = f0 + mi * 16 + q * 4;
#pragma unroll
        for (int ni = 0; ni < NW; ++ni) {
            int b = b0 + ni * 16 + c;
            epilogue_store(Xout + ((size_t)n * 128 + b) * CF + fbase,
                           acc[0][mi][ni], acc[1][mi][ni], bias, fbase, s0, s1);
        }
    }
}

// ============================================================================
// FC head: h bf16 [128][1024]; out [128][16] fp32 log-softmax
// ============================================================================
__global__ __launch_bounds__(256) void fc_logsoftmax_kernel(
    const unsigned short* __restrict__ h, const float* __restrict__ fcW,
    const float* __restrict__ fcb, float* __restrict__ out)
{
    int b   = blockIdx.x;
    int tid = threadIdx.x;
    int k     = tid & 15;
    int chunk = tid >> 4;

    const float* __restrict__ wk = fcW + (size_t)k * 1024;
    const unsigned short* hb = h + (size_t)b * 1024;

    float partial = 0.0f;
    int j0 = chunk * 64;
#pragma unroll 8
    for (int j = 0; j < 64; ++j)
        partial = fmaf(bf2f(hb[j0 + j]), wk[j0 + j], partial);

    __shared__ float red[16][17];
    red[chunk][k] = partial;
    __syncthreads();

    __shared__ float logits[16];
    if (tid < 16) {
        float s = fcb[tid];
#pragma unroll
        for (int c = 0; c < 16; ++c) s += red[c][tid];
        logits[tid] = s;
    }
    __syncthreads();

    if (tid < 16) {
        float mx = -INFINITY;
#pragma unroll
        for (int kk = 0; kk < 16; ++kk) mx = fmaxf(mx, logits[kk]);
        float se = 0.0f;
#pragma unroll
        for (int kk = 0; kk < 16; ++kk) se += expf(logits[kk] - mx);
        out[b * 16 + tid] = logits[tid] - mx - logf(se);
    }
}

// ============================================================================
extern "C" void kernel_launch(void* const* d_in, const int* in_sizes, int n_in,
                              void* d_out, int out_size, void* d_ws, size_t ws_size,
                              hipStream_t stream)
{
#define WL(i) (const float*)d_in[1 + 3 * (i)]
#define BL(i) (const float*)d_in[2 + 3 * (i)]
#define SL(i) (const int*)  d_in[3 + 3 * (i)]

    unsigned short* bufA = (unsigned short*)d_ws;          // 4 MB
    unsigned short* bufB = bufA + 2u * 1024u * 1024u;      // 4 MB
    unsigned short* Wb   = bufB + 2u * 1024u * 1024u;      // packed W6..W11 (~7 MB)

    // Wb offsets (W6,W7,W8,W9,W10,W11)
    const int o6 = 0, o7 = 24576, o8 = 122880, o9 = 516096, o10 = 1302528, o11 = 2088960;

    // ---- K1: pack(W6..W11) || L1+L2 -> X3 (bufA) ----
    K1Params P;
    P.x = (const float*)d_in[0];
    P.W1 = WL(0); P.B1 = BL(0); P.S1 = SL(0);
    P.W2 = WL(1); P.B2 = BL(1); P.S2 = SL(1);
    for (int i = 0; i < 6; ++i) P.Wsrc[i] = WL(5 + i);     // W6..W11
    P.Wb = Wb; P.X3 = bufA;
    k1_kernel<<<192, 256, 0, stream>>>(P);

    // ---- K2: L3+L4+L5 -> X6 (bufB) ----
    stage2_kernel<<<256, 256, 0, stream>>>(bufA,
        WL(2), BL(2), SL(2), WL(3), BL(3), SL(3), WL(4), BL(4), SL(4), bufB);

    // ---- K3: L6+L7+L8 -> X9 (bufA) ----
    stage3_kernel<<<64, 512, 0, stream>>>(bufB,
        Wb + o6, BL(5), SL(5), Wb + o7, BL(6), SL(6), Wb + o8, BL(7), SL(7), bufA);

    // ---- K4..K6: L9, L10, L11 ----
    mfma_kernel<512, 512, 4, 1, 2><<<128, 256, 0, stream>>>(bufA, Wb + o9,  BL(8),  SL(8),  bufB);
    mfma_kernel<512, 512, 2, 1, 2><<<64, 256, 0, stream>>>(bufB, Wb + o10, BL(9),  SL(9),  bufA);
    mfma_kernel<512, 1024, 1, 1, 2><<<64, 256, 0, stream>>>(bufA, Wb + o11, BL(10), SL(10), bufB);

    // ---- K7: FC ----
    fc_logsoftmax_kernel<<<128, 256, 0, stream>>>(bufB, (const float*)d_in[34], (const float*)d_in[35], (float*)d_out);

#undef WL
#undef BL
#undef SL
}

// Round 12
// 217.772 us; speedup vs baseline: 3.0194x; 1.0900x over previous
//
#include <hip/hip_runtime.h>
#include <math.h>

typedef __attribute__((ext_vector_type(8))) short bf16x8;
typedef __attribute__((ext_vector_type(4))) float f32x4;

__device__ __forceinline__ unsigned short f2bf(float f) {
    unsigned u = __builtin_bit_cast(unsigned, f);
    u += 0x7FFF + ((u >> 16) & 1);          // RNE
    return (unsigned short)(u >> 16);
}
__device__ __forceinline__ float bf2f(unsigned short h) {
    unsigned u = ((unsigned)h) << 16;
    return __builtin_bit_cast(float, u);
}

// ============================================================================
// K1: [blocks 0..127] L1+L2 fused via LDS  |  [blocks 128..255] pack W3..W11
// ============================================================================
struct K1Params {
    const float* x;
    const float* W1; const float* B1; const int* S1;
    const float* W2; const float* B2; const int* S2;
    const float* Wsrc[9];          // W3..W11 fp32
    unsigned short* Wb;            // packed bf16 out
    unsigned short* X3;
};

__global__ __launch_bounds__(256) void k1_kernel(K1Params P)
{
    const int tid = threadIdx.x;

    if (blockIdx.x >= 128) {
        // ---- pack W3..W11 fp32 -> bf16 (128 blocks, 32768 threads) ----
        int gt = (blockIdx.x - 128) * 256 + tid;
        const int we[9] = {6144, 12288, 12288, 24576, 98304, 393216, 786432, 786432, 1572864};
        int off = 0;
#pragma unroll
        for (int li = 0; li < 9; ++li) {
            const float4* src = (const float4*)P.Wsrc[li];
            ushort4* dst = (ushort4*)(P.Wb + off);
            int n4 = we[li] >> 2;
            for (int i = gt; i < n4; i += 32768) {
                float4 w = src[i];
                dst[i] = make_ushort4(f2bf(w.x), f2bf(w.y), f2bf(w.z), f2bf(w.w));
            }
            off += we[li];
        }
        return;
    }

    __shared__ float wl1[72], bl1[24], wl2[768], bl2[96];
    __shared__ unsigned short bufL1[16 * 64 * 8];

    if (tid < 72) wl1[tid] = P.W1[tid];
    if (tid >= 128 && tid < 152) bl1[tid - 128] = P.B1[tid - 128];
    for (int i = tid; i < 768; i += 256) wl2[i] = P.W2[i];
    if (tid < 96) bl2[tid] = P.B2[tid];
    __syncthreads();

    const int npT = blockIdx.x >> 1;          // 0..63
    const int b0  = (blockIdx.x & 1) * 64;

    // ---- L1: 16 L1-out positions x 64 b ----
    for (int i = tid; i < 1024; i += 256) {
        int pos_l = i >> 6, bl = i & 63;
        int np1 = npT * 16 + pos_l;
        int b = b0 + bl;
        int s0 = P.S1[2 * np1], s1 = P.S1[2 * np1 + 1];
        const float* xb = P.x + (size_t)b * 6144 + 2 * np1;
        float2 c0 = *(const float2*)(xb);
        float2 c1 = *(const float2*)(xb + 2048);
        float2 c2 = *(const float2*)(xb + 4096);
        unsigned short o[8];
#pragma unroll
        for (int f = 0; f < 8; ++f) {
            int r0 = f * 3 + s0, r1 = f * 3 + s1;
            float z0 = fmaf(wl1[r0*3+2], c2.x, fmaf(wl1[r0*3+1], c1.x, fmaf(wl1[r0*3+0], c0.x, bl1[r0])));
            float z1 = fmaf(wl1[r1*3+2], c2.y, fmaf(wl1[r1*3+1], c1.y, fmaf(wl1[r1*3+0], c0.y, bl1[r1])));
            o[f] = f2bf(fmaxf(fmaxf(z0, z1), 0.f));
        }
        unsigned short* dst = &bufL1[((size_t)pos_l * 64 + bl) * 8];
        *(ushort4*)dst       = make_ushort4(o[0], o[1], o[2], o[3]);
        *(ushort4*)(dst + 4) = make_ushort4(o[4], o[5], o[6], o[7]);
    }
    __syncthreads();

    // ---- L2: 8 L2-out positions x 64 b ----
    for (int i = tid; i < 512; i += 256) {
        int np_l = i >> 6, bl = i & 63;
        int np2 = npT * 8 + np_l;
        int s0 = P.S2[2 * np2], s1 = P.S2[2 * np2 + 1];
        const unsigned short* r0 = &bufL1[((size_t)(2 * np_l) * 64 + bl) * 8];
        const unsigned short* r1 = &bufL1[((size_t)(2 * np_l + 1) * 64 + bl) * 8];
        float xa[8], xb[8];
        {
            ushort4 u0 = *(const ushort4*)r0, u1 = *(const ushort4*)(r0 + 4);
            ushort4 v0 = *(const ushort4*)r1, v1 = *(const ushort4*)(r1 + 4);
            xa[0]=bf2f(u0.x); xa[1]=bf2f(u0.y); xa[2]=bf2f(u0.z); xa[3]=bf2f(u0.w);
            xa[4]=bf2f(u1.x); xa[5]=bf2f(u1.y); xa[6]=bf2f(u1.z); xa[7]=bf2f(u1.w);
            xb[0]=bf2f(v0.x); xb[1]=bf2f(v0.y); xb[2]=bf2f(v0.z); xb[3]=bf2f(v0.w);
            xb[4]=bf2f(v1.x); xb[5]=bf2f(v1.y); xb[6]=bf2f(v1.z); xb[7]=bf2f(v1.w);
        }
        unsigned short o[32];
#pragma unroll
        for (int f = 0; f < 32; ++f) {
            const float* w0 = &wl2[(f * 3 + s0) * 8];
            const float* w1 = &wl2[(f * 3 + s1) * 8];
            float z0 = bl2[f * 3 + s0], z1 = bl2[f * 3 + s1];
#pragma unroll
            for (int k = 0; k < 8; ++k) {
                z0 = fmaf(w0[k], xa[k], z0);
                z1 = fmaf(w1[k], xb[k], z1);
            }
            o[f] = f2bf(fmaxf(fmaxf(z0, z1), 0.f));
        }
        unsigned short* dst = P.X3 + ((size_t)np2 * 128 + b0 + bl) * 32;
#pragma unroll
        for (int i2 = 0; i2 < 8; ++i2)
            *(ushort4*)(dst + 4 * i2) = make_ushort4(o[4*i2], o[4*i2+1], o[4*i2+2], o[4*i2+3]);
    }
}

// ============================================================================
// MFMA helpers (verified R9/R11)
// ============================================================================
template<int CIN>
__device__ __forceinline__ void mfma_tile(
    const unsigned short* a0, const unsigned short* a1,
    const unsigned short* b0p, const unsigned short* b1p,
    f32x4& acc0, f32x4& acc1)
{
#pragma unroll
    for (int k = 0; k < CIN; k += 32) {
        bf16x8 A0 = __builtin_bit_cast(bf16x8, *(const float4*)(const void*)(a0 + k));
        bf16x8 A1 = __builtin_bit_cast(bf16x8, *(const float4*)(const void*)(a1 + k));
        bf16x8 B0 = __builtin_bit_cast(bf16x8, *(const float4*)(const void*)(b0p + k));
        bf16x8 B1 = __builtin_bit_cast(bf16x8, *(const float4*)(const void*)(b1p + k));
        acc0 = __builtin_amdgcn_mfma_f32_16x16x32_bf16(A0, B0, acc0, 0, 0, 0);
        acc1 = __builtin_amdgcn_mfma_f32_16x16x32_bf16(A1, B1, acc1, 0, 0, 0);
    }
}

// B-frag read helper for padded-LDS rows (row stride RPE elems): k-chunks are
// contiguous 16B within a row, rows padded so lane banks alias only 2-way.
template<int CIN, int RPE>
__device__ __forceinline__ void mfma_tile_lds(
    const unsigned short* a0, const unsigned short* a1,
    const unsigned short* b0p, const unsigned short* b1p,
    f32x4& acc0, f32x4& acc1)
{
#pragma unroll
    for (int k = 0; k < CIN; k += 32) {
        bf16x8 A0 = __builtin_bit_cast(bf16x8, *(const float4*)(const void*)(a0 + k));
        bf16x8 A1 = __builtin_bit_cast(bf16x8, *(const float4*)(const void*)(a1 + k));
        bf16x8 B0 = __builtin_bit_cast(bf16x8, *(const float4*)(const void*)(b0p + k));
        bf16x8 B1 = __builtin_bit_cast(bf16x8, *(const float4*)(const void*)(b1p + k));
        acc0 = __builtin_amdgcn_mfma_f32_16x16x32_bf16(A0, B0, acc0, 0, 0, 0);
        acc1 = __builtin_amdgcn_mfma_f32_16x16x32_bf16(A1, B1, acc1, 0, 0, 0);
    }
}

__device__ __forceinline__ void epilogue_store(
    unsigned short* dst, const f32x4& acc0, const f32x4& acc1,
    const float* bias, int fbase, int s0, int s1)
{
    unsigned short o[4];
#pragma unroll
    for (int r = 0; r < 4; ++r) {
        float v = fmaxf(fmaxf(acc0[r] + bias[(fbase + r) * 3 + s0],
                              acc1[r] + bias[(fbase + r) * 3 + s1]), 0.f);
        o[r] = f2bf(v);
    }
    *(ushort4*)dst = make_ushort4(o[0], o[1], o[2], o[3]);
}

// ============================================================================
// K2: L3+L4+L5 fused. 256 blocks (n5 x 4 b-quarters). W from GLOBAL packed Wb
// (no LDS W). LDS intermediates padded: row stride 72 elems -> 2-way bank
// aliasing only (free). X3 [512][128][32] -> X6 [64][128][64]
// ============================================================================
__global__ __launch_bounds__(256) void stage2_kernel(
    const unsigned short* __restrict__ X3,
    const unsigned short* __restrict__ Wb,   // W3@0, W4@6144, W5@18432
    const float* __restrict__ B3, const int* __restrict__ S3,
    const float* __restrict__ B4, const int* __restrict__ S4,
    const float* __restrict__ B5, const int* __restrict__ S5,
    unsigned short* __restrict__ X6)
{
    constexpr int RPE = 72;                       // padded row stride (elems)
    __shared__ unsigned short L3o[4 * 32 * RPE];  // 18.4 KB
    __shared__ unsigned short L4o[2 * 32 * RPE];  //  9.2 KB

    const int tid  = threadIdx.x;
    const int lane = tid & 63;
    const int wv   = tid >> 6;
    const int c = lane & 15, q = lane >> 4;
    const int n5 = blockIdx.x >> 2;
    const int b0 = (blockIdx.x & 3) * 32;

    const unsigned short* W3b = Wb;
    const unsigned short* W4b = Wb + 6144;
    const unsigned short* W5b = Wb + 18432;

    // ---- L3 (CIN=32): j=0..3 (global pos 4n5+j), B from global X3 ----
    for (int t = wv; t < 32; t += 4) {
        int bt = t & 1, ft = (t >> 1) & 3, j = t >> 3;
        int np = 4 * n5 + j;
        int s0 = __builtin_amdgcn_readfirstlane(S3[2 * np]);
        int s1 = __builtin_amdgcn_readfirstlane(S3[2 * np + 1]);
        int f0 = ft * 16, bl = bt * 16;
        const unsigned short* a0 = W3b + (size_t)((f0 + c) * 3 + s0) * 32 + q * 8;
        const unsigned short* a1 = W3b + (size_t)((f0 + c) * 3 + s1) * 32 + q * 8;
        const unsigned short* bp0 = X3 + ((size_t)(8 * n5 + 2 * j) * 128 + b0 + bl + c) * 32 + q * 8;
        const unsigned short* bp1 = X3 + ((size_t)(8 * n5 + 2 * j + 1) * 128 + b0 + bl + c) * 32 + q * 8;
        f32x4 acc0 = {0.f,0.f,0.f,0.f}, acc1 = {0.f,0.f,0.f,0.f};
        mfma_tile<32>(a0, a1, bp0, bp1, acc0, acc1);
        epilogue_store(&L3o[((size_t)j * 32 + bl + c) * RPE + f0 + q * 4],
                       acc0, acc1, B3, f0 + q * 4, s0, s1);
    }
    __syncthreads();

    // ---- L4 (CIN=64): j=0..1 (global pos 2n5+j), B from L3o ----
    for (int t = wv; t < 16; t += 4) {
        int bt = t & 1, ft = (t >> 1) & 3, j = t >> 3;
        int np = 2 * n5 + j;
        int s0 = __builtin_amdgcn_readfirstlane(S4[2 * np]);
        int s1 = __builtin_amdgcn_readfirstlane(S4[2 * np + 1]);
        int f0 = ft * 16, bl = bt * 16;
        const unsigned short* a0 = W4b + (size_t)((f0 + c) * 3 + s0) * 64 + q * 8;
        const unsigned short* a1 = W4b + (size_t)((f0 + c) * 3 + s1) * 64 + q * 8;
        const unsigned short* bp0 = &L3o[((size_t)(2 * j) * 32 + bl + c) * RPE + q * 8];
        const unsigned short* bp1 = &L3o[((size_t)(2 * j + 1) * 32 + bl + c) * RPE + q * 8];
        f32x4 acc0 = {0.f,0.f,0.f,0.f}, acc1 = {0.f,0.f,0.f,0.f};
        mfma_tile_lds<64, RPE>(a0, a1, bp0, bp1, acc0, acc1);
        epilogue_store(&L4o[((size_t)j * 32 + bl + c) * RPE + f0 + q * 4],
                       acc0, acc1, B4, f0 + q * 4, s0, s1);
    }
    __syncthreads();

    // ---- L5 (CIN=64): out pos n5, B from L4o -> global X6 ----
    for (int t = wv; t < 8; t += 4) {
        int bt = t & 1, ft = t >> 1;
        int s0 = __builtin_amdgcn_readfirstlane(S5[2 * n5]);
        int s1 = __builtin_amdgcn_readfirstlane(S5[2 * n5 + 1]);
        int f0 = ft * 16, bl = bt * 16;
        const unsigned short* a0 = W5b + (size_t)((f0 + c) * 3 + s0) * 64 + q * 8;
        const unsigned short* a1 = W5b + (size_t)((f0 + c) * 3 + s1) * 64 + q * 8;
        const unsigned short* bp0 = &L4o[((size_t)(0) * 32 + bl + c) * RPE + q * 8];
        const unsigned short* bp1 = &L4o[((size_t)(1) * 32 + bl + c) * RPE + q * 8];
        f32x4 acc0 = {0.f,0.f,0.f,0.f}, acc1 = {0.f,0.f,0.f,0.f};
        mfma_tile_lds<64, RPE>(a0, a1, bp0, bp1, acc0, acc1);
        epilogue_store(X6 + ((size_t)n5 * 128 + b0 + bl + c) * 64 + f0 + q * 4,
                       acc0, acc1, B5, f0 + q * 4, s0, s1);
    }
}

// ============================================================================
// Flat MFMA layer (L6..L11): verified R9 body.
// ============================================================================
template<int CIN, int CF, int NP, int MW, int NW>
__global__ __launch_bounds__(256) void mfma_kernel(
    const unsigned short* __restrict__ Xin,
    const unsigned short* __restrict__ Wb,
    const float* __restrict__ bias,
    const int*   __restrict__ sel,
    unsigned short* __restrict__ Xout)
{
    constexpr int FT = CF / (16 * MW);
    constexpr int BT = 128 / (16 * NW);

    const int wid  = threadIdx.x >> 6;
    const int lane = threadIdx.x & 63;
    const int task = blockIdx.x * 4 + wid;
    const int bi = task % BT;
    const int fi = (task / BT) % FT;
    const int n  = task / (BT * FT);

    const int c = lane & 15;
    const int q = lane >> 4;
    const int s0 = __builtin_amdgcn_readfirstlane(sel[2 * n]);
    const int s1 = __builtin_amdgcn_readfirstlane(sel[2 * n + 1]);

    const int f0 = fi * 16 * MW;
    const int b0 = bi * 16 * NW;

    const unsigned short* ap[2][MW];
    const unsigned short* bp[2][NW];
#pragma unroll
    for (int p = 0; p < 2; ++p) {
        int s = p ? s1 : s0;
#pragma unroll
        for (int mi = 0; mi < MW; ++mi)
            ap[p][mi] = Wb + (size_t)((f0 + mi * 16 + c) * 3 + s) * CIN + q * 8;
#pragma unroll
        for (int ni = 0; ni < NW; ++ni)
            bp[p][ni] = Xin + ((size_t)(2 * n + p) * 128 + b0 + ni * 16 + c) * CIN + q * 8;
    }

    f32x4 acc[2][MW][NW];
#pragma unroll
    for (int p = 0; p < 2; ++p)
#pragma unroll
        for (int mi = 0; mi < MW; ++mi)
#pragma unroll
            for (int ni = 0; ni < NW; ++ni)
                acc[p][mi][ni] = (f32x4){0.f, 0.f, 0.f, 0.f};

#pragma unroll 2
    for (int k = 0; k < CIN; k += 32) {
        bf16x8 A[2][MW], B[2][NW];
#pragma unroll
        for (int p = 0; p < 2; ++p) {
#pragma unroll
            for (int mi = 0; mi < MW; ++mi)
                A[p][mi] = __builtin_bit_cast(bf16x8, *(const float4*)(const void*)(ap[p][mi] + k));
#pragma unroll
            for (int ni = 0; ni < NW; ++ni)
                B[p][ni] = __builtin_bit_cast(bf16x8, *(const float4*)(const void*)(bp[p][ni] + k));
        }
#pragma unroll
        for (int p = 0; p < 2; ++p)
#pragma unroll
            for (int mi = 0; mi < MW; ++mi)
#pragma unroll
                for (int ni = 0; ni < NW; ++ni)
                    acc[p][mi][ni] = __builtin_amdgcn_mfma_f32_16x16x32_bf16(
                        A[p][mi], B[p][ni], acc[p][mi][ni], 0, 0, 0);
    }

#pragma unroll
    for (int mi = 0; mi < MW; ++mi) {
        int fbase = f0 + mi * 16 + q * 4;
#pragma unroll
        for (int ni = 0; ni < NW; ++ni) {
            int b = b0 + ni * 16 + c;
            epilogue_store(Xout + ((size_t)n * 128 + b) * CF + fbase,
                           acc[0][mi][ni], acc[1][mi][ni], bias, fbase, s0, s1);
        }
    }
}

// ============================================================================
// FC head: h bf16 [128][1024]; out [128][16] fp32 log-softmax
// ============================================================================
__global__ __launch_bounds__(256) void fc_logsoftmax_kernel(
    const unsigned short* __restrict__ h, const float* __restrict__ fcW,
    const float* __restrict__ fcb, float* __restrict__ out)
{
    int b   = blockIdx.x;
    int tid = threadIdx.x;
    int k     = tid & 15;
    int chunk = tid >> 4;

    const float* __restrict__ wk = fcW + (size_t)k * 1024;
    const unsigned short* hb = h + (size_t)b * 1024;

    float partial = 0.0f;
    int j0 = chunk * 64;
#pragma unroll 8
    for (int j = 0; j < 64; ++j)
        partial = fmaf(bf2f(hb[j0 + j]), wk[j0 + j], partial);

    __shared__ float red[16][17];
    red[chunk][k] = partial;
    __syncthreads();

    __shared__ float logits[16];
    if (tid < 16) {
        float s = fcb[tid];
#pragma unroll
        for (int c = 0; c < 16; ++c) s += red[c][tid];
        logits[tid] = s;
    }
    __syncthreads();

    if (tid < 16) {
        float mx = -INFINITY;
#pragma unroll
        for (int kk = 0; kk < 16; ++kk) mx = fmaxf(mx, logits[kk]);
        float se = 0.0f;
#pragma unroll
        for (int kk = 0; kk < 16; ++kk) se += expf(logits[kk] - mx);
        out[b * 16 + tid] = logits[tid] - mx - logf(se);
    }
}

// ============================================================================
extern "C" void kernel_launch(void* const* d_in, const int* in_sizes, int n_in,
                              void* d_out, int out_size, void* d_ws, size_t ws_size,
                              hipStream_t stream)
{
#define WL(i) (const float*)d_in[1 + 3 * (i)]
#define BL(i) (const float*)d_in[2 + 3 * (i)]
#define SL(i) (const int*)  d_in[3 + 3 * (i)]

    unsigned short* bufA = (unsigned short*)d_ws;          // 4 MB
    unsigned short* bufB = bufA + 2u * 1024u * 1024u;      // 4 MB
    unsigned short* Wb   = bufB + 2u * 1024u * 1024u;      // packed W3..W11 bf16

    // Wb offsets
    const int o3 = 0, o4 = 6144, o5 = 18432, o6 = 30720, o7 = 55296,
              o8 = 153600, o9 = 546816, o10 = 1333248, o11 = 2119680;
    (void)o3; (void)o4; (void)o5;

    // ---- K1: pack(W3..W11) || L1+L2 -> X3 (bufA) ----
    K1Params P;
    P.x = (const float*)d_in[0];
    P.W1 = WL(0); P.B1 = BL(0); P.S1 = SL(0);
    P.W2 = WL(1); P.B2 = BL(1); P.S2 = SL(1);
    for (int i = 0; i < 9; ++i) P.Wsrc[i] = WL(2 + i);     // W3..W11
    P.Wb = Wb; P.X3 = bufA;
    k1_kernel<<<256, 256, 0, stream>>>(P);

    // ---- K2: L3+L4+L5 -> X6 (bufB) ----
    stage2_kernel<<<256, 256, 0, stream>>>(bufA, Wb,
        BL(2), SL(2), BL(3), SL(3), BL(4), SL(4), bufB);

    // ---- K3..K8: flat MFMA layers ----
    mfma_kernel<64, 128, 32, 2, 2><<<128, 256, 0, stream>>>(bufB, Wb + o6,  BL(5),  SL(5),  bufA);
    mfma_kernel<128, 256, 16, 2, 2><<<128, 256, 0, stream>>>(bufA, Wb + o7,  BL(6),  SL(6),  bufB);
    mfma_kernel<256, 512, 8, 2, 2><<<128, 256, 0, stream>>>(bufB, Wb + o8,  BL(7),  SL(7),  bufA);
    mfma_kernel<512, 512, 4, 1, 2><<<128, 256, 0, stream>>>(bufA, Wb + o9,  BL(8),  SL(8),  bufB);
    mfma_kernel<512, 512, 2, 1, 2><<<64, 256, 0, stream>>>(bufB, Wb + o10, BL(9),  SL(9),  bufA);
    mfma_kernel<512, 1024, 1, 1, 2><<<64, 256, 0, stream>>>(bufA, Wb + o11, BL(10), SL(10), bufB);

    // ---- K9: FC ----
    fc_logsoftmax_kernel<<<128, 256, 0, stream>>>(bufB, (const float*)d_in[34], (const float*)d_in[35], (float*)d_out);

#undef WL
#undef BL
#undef SL
}

// Round 13
// 212.732 us; speedup vs baseline: 3.0909x; 1.0237x over previous
//
#include <hip/hip_runtime.h>
#include <math.h>

typedef __attribute__((ext_vector_type(8))) short bf16x8;
typedef __attribute__((ext_vector_type(4))) float f32x4;

__device__ __forceinline__ unsigned short f2bf(float f) {
    unsigned u = __builtin_bit_cast(unsigned, f);
    u += 0x7FFF + ((u >> 16) & 1);          // RNE
    return (unsigned short)(u >> 16);
}
__device__ __forceinline__ float bf2f(unsigned short h) {
    unsigned u = ((unsigned)h) << 16;
    return __builtin_bit_cast(float, u);
}

// ============================================================================
// K1: [blocks 0..127] L1+L2 fused via LDS  |  [blocks 128..255] pack W3..W11
// ============================================================================
struct K1Params {
    const float* x;
    const float* W1; const float* B1; const int* S1;
    const float* W2; const float* B2; const int* S2;
    const float* Wsrc[9];          // W3..W11 fp32
    unsigned short* Wb;            // packed bf16 out
    unsigned short* X3;
};

__global__ __launch_bounds__(256) void k1_kernel(K1Params P)
{
    const int tid = threadIdx.x;

    if (blockIdx.x >= 128) {
        int gt = (blockIdx.x - 128) * 256 + tid;
        const int we[9] = {6144, 12288, 12288, 24576, 98304, 393216, 786432, 786432, 1572864};
        int off = 0;
#pragma unroll
        for (int li = 0; li < 9; ++li) {
            const float4* src = (const float4*)P.Wsrc[li];
            ushort4* dst = (ushort4*)(P.Wb + off);
            int n4 = we[li] >> 2;
            for (int i = gt; i < n4; i += 32768) {
                float4 w = src[i];
                dst[i] = make_ushort4(f2bf(w.x), f2bf(w.y), f2bf(w.z), f2bf(w.w));
            }
            off += we[li];
        }
        return;
    }

    __shared__ float wl1[72], bl1[24], wl2[768], bl2[96];
    __shared__ unsigned short bufL1[16 * 64 * 8];

    if (tid < 72) wl1[tid] = P.W1[tid];
    if (tid >= 128 && tid < 152) bl1[tid - 128] = P.B1[tid - 128];
    for (int i = tid; i < 768; i += 256) wl2[i] = P.W2[i];
    if (tid < 96) bl2[tid] = P.B2[tid];
    __syncthreads();

    const int npT = blockIdx.x >> 1;          // 0..63
    const int b0  = (blockIdx.x & 1) * 64;

    for (int i = tid; i < 1024; i += 256) {
        int pos_l = i >> 6, bl = i & 63;
        int np1 = npT * 16 + pos_l;
        int b = b0 + bl;
        int s0 = P.S1[2 * np1], s1 = P.S1[2 * np1 + 1];
        const float* xb = P.x + (size_t)b * 6144 + 2 * np1;
        float2 c0 = *(const float2*)(xb);
        float2 c1 = *(const float2*)(xb + 2048);
        float2 c2 = *(const float2*)(xb + 4096);
        unsigned short o[8];
#pragma unroll
        for (int f = 0; f < 8; ++f) {
            int r0 = f * 3 + s0, r1 = f * 3 + s1;
            float z0 = fmaf(wl1[r0*3+2], c2.x, fmaf(wl1[r0*3+1], c1.x, fmaf(wl1[r0*3+0], c0.x, bl1[r0])));
            float z1 = fmaf(wl1[r1*3+2], c2.y, fmaf(wl1[r1*3+1], c1.y, fmaf(wl1[r1*3+0], c0.y, bl1[r1])));
            o[f] = f2bf(fmaxf(fmaxf(z0, z1), 0.f));
        }
        unsigned short* dst = &bufL1[((size_t)pos_l * 64 + bl) * 8];
        *(ushort4*)dst       = make_ushort4(o[0], o[1], o[2], o[3]);
        *(ushort4*)(dst + 4) = make_ushort4(o[4], o[5], o[6], o[7]);
    }
    __syncthreads();

    for (int i = tid; i < 512; i += 256) {
        int np_l = i >> 6, bl = i & 63;
        int np2 = npT * 8 + np_l;
        int s0 = P.S2[2 * np2], s1 = P.S2[2 * np2 + 1];
        const unsigned short* r0 = &bufL1[((size_t)(2 * np_l) * 64 + bl) * 8];
        const unsigned short* r1 = &bufL1[((size_t)(2 * np_l + 1) * 64 + bl) * 8];
        float xa[8], xb[8];
        {
            ushort4 u0 = *(const ushort4*)r0, u1 = *(const ushort4*)(r0 + 4);
            ushort4 v0 = *(const ushort4*)r1, v1 = *(const ushort4*)(r1 + 4);
            xa[0]=bf2f(u0.x); xa[1]=bf2f(u0.y); xa[2]=bf2f(u0.z); xa[3]=bf2f(u0.w);
            xa[4]=bf2f(u1.x); xa[5]=bf2f(u1.y); xa[6]=bf2f(u1.z); xa[7]=bf2f(u1.w);
            xb[0]=bf2f(v0.x); xb[1]=bf2f(v0.y); xb[2]=bf2f(v0.z); xb[3]=bf2f(v0.w);
            xb[4]=bf2f(v1.x); xb[5]=bf2f(v1.y); xb[6]=bf2f(v1.z); xb[7]=bf2f(v1.w);
        }
        unsigned short o[32];
#pragma unroll
        for (int f = 0; f < 32; ++f) {
            const float* w0 = &wl2[(f * 3 + s0) * 8];
            const float* w1 = &wl2[(f * 3 + s1) * 8];
            float z0 = bl2[f * 3 + s0], z1 = bl2[f * 3 + s1];
#pragma unroll
            for (int k = 0; k < 8; ++k) {
                z0 = fmaf(w0[k], xa[k], z0);
                z1 = fmaf(w1[k], xb[k], z1);
            }
            o[f] = f2bf(fmaxf(fmaxf(z0, z1), 0.f));
        }
        unsigned short* dst = P.X3 + ((size_t)np2 * 128 + b0 + bl) * 32;
#pragma unroll
        for (int i2 = 0; i2 < 8; ++i2)
            *(ushort4*)(dst + 4 * i2) = make_ushort4(o[4*i2], o[4*i2+1], o[4*i2+2], o[4*i2+3]);
    }
}

// ============================================================================
// MFMA helpers (verified R9/R11/R12)
// ============================================================================
template<int CIN>
__device__ __forceinline__ void mfma_tile(
    const unsigned short* a0, const unsigned short* a1,
    const unsigned short* b0p, const unsigned short* b1p,
    f32x4& acc0, f32x4& acc1)
{
#pragma unroll
    for (int k = 0; k < CIN; k += 32) {
        bf16x8 A0 = __builtin_bit_cast(bf16x8, *(const float4*)(const void*)(a0 + k));
        bf16x8 A1 = __builtin_bit_cast(bf16x8, *(const float4*)(const void*)(a1 + k));
        bf16x8 B0 = __builtin_bit_cast(bf16x8, *(const float4*)(const void*)(b0p + k));
        bf16x8 B1 = __builtin_bit_cast(bf16x8, *(const float4*)(const void*)(b1p + k));
        acc0 = __builtin_amdgcn_mfma_f32_16x16x32_bf16(A0, B0, acc0, 0, 0, 0);
        acc1 = __builtin_amdgcn_mfma_f32_16x16x32_bf16(A1, B1, acc1, 0, 0, 0);
    }
}

__device__ __forceinline__ void epilogue_store(
    unsigned short* dst, const f32x4& acc0, const f32x4& acc1,
    const float* bias, int fbase, int s0, int s1)
{
    unsigned short o[4];
#pragma unroll
    for (int r = 0; r < 4; ++r) {
        float v = fmaxf(fmaxf(acc0[r] + bias[(fbase + r) * 3 + s0],
                              acc1[r] + bias[(fbase + r) * 3 + s1]), 0.f);
        o[r] = f2bf(v);
    }
    *(ushort4*)dst = make_ushort4(o[0], o[1], o[2], o[3]);
}

// ============================================================================
// K2: L3+L4+L5 fused. 256 blocks (n5 x 4 b-quarters). W from GLOBAL packed Wb.
// LDS intermediates padded (stride 72) -> 2-way bank aliasing only (free).
// X3 [512][128][32] -> X6 [64][128][64]
// ============================================================================
__global__ __launch_bounds__(256) void stage2_kernel(
    const unsigned short* __restrict__ X3,
    const unsigned short* __restrict__ Wb,   // W3@0, W4@6144, W5@18432
    const float* __restrict__ B3, const int* __restrict__ S3,
    const float* __restrict__ B4, const int* __restrict__ S4,
    const float* __restrict__ B5, const int* __restrict__ S5,
    unsigned short* __restrict__ X6)
{
    constexpr int RPE = 72;
    __shared__ unsigned short L3o[4 * 32 * RPE];
    __shared__ unsigned short L4o[2 * 32 * RPE];

    const int tid  = threadIdx.x;
    const int lane = tid & 63;
    const int wv   = tid >> 6;
    const int c = lane & 15, q = lane >> 4;
    const int n5 = blockIdx.x >> 2;
    const int b0 = (blockIdx.x & 3) * 32;

    const unsigned short* W3b = Wb;
    const unsigned short* W4b = Wb + 6144;
    const unsigned short* W5b = Wb + 18432;

    for (int t = wv; t < 32; t += 4) {
        int bt = t & 1, ft = (t >> 1) & 3, j = t >> 3;
        int np = 4 * n5 + j;
        int s0 = __builtin_amdgcn_readfirstlane(S3[2 * np]);
        int s1 = __builtin_amdgcn_readfirstlane(S3[2 * np + 1]);
        int f0 = ft * 16, bl = bt * 16;
        const unsigned short* a0 = W3b + (size_t)((f0 + c) * 3 + s0) * 32 + q * 8;
        const unsigned short* a1 = W3b + (size_t)((f0 + c) * 3 + s1) * 32 + q * 8;
        const unsigned short* bp0 = X3 + ((size_t)(8 * n5 + 2 * j) * 128 + b0 + bl + c) * 32 + q * 8;
        const unsigned short* bp1 = X3 + ((size_t)(8 * n5 + 2 * j + 1) * 128 + b0 + bl + c) * 32 + q * 8;
        f32x4 acc0 = {0.f,0.f,0.f,0.f}, acc1 = {0.f,0.f,0.f,0.f};
        mfma_tile<32>(a0, a1, bp0, bp1, acc0, acc1);
        epilogue_store(&L3o[((size_t)j * 32 + bl + c) * RPE + f0 + q * 4],
                       acc0, acc1, B3, f0 + q * 4, s0, s1);
    }
    __syncthreads();

    for (int t = wv; t < 16; t += 4) {
        int bt = t & 1, ft = (t >> 1) & 3, j = t >> 3;
        int np = 2 * n5 + j;
        int s0 = __builtin_amdgcn_readfirstlane(S4[2 * np]);
        int s1 = __builtin_amdgcn_readfirstlane(S4[2 * np + 1]);
        int f0 = ft * 16, bl = bt * 16;
        const unsigned short* a0 = W4b + (size_t)((f0 + c) * 3 + s0) * 64 + q * 8;
        const unsigned short* a1 = W4b + (size_t)((f0 + c) * 3 + s1) * 64 + q * 8;
        const unsigned short* bp0 = &L3o[((size_t)(2 * j) * 32 + bl + c) * RPE + q * 8];
        const unsigned short* bp1 = &L3o[((size_t)(2 * j + 1) * 32 + bl + c) * RPE + q * 8];
        f32x4 acc0 = {0.f,0.f,0.f,0.f}, acc1 = {0.f,0.f,0.f,0.f};
        mfma_tile<64>(a0, a1, bp0, bp1, acc0, acc1);
        epilogue_store(&L4o[((size_t)j * 32 + bl + c) * RPE + f0 + q * 4],
                       acc0, acc1, B4, f0 + q * 4, s0, s1);
    }
    __syncthreads();

    for (int t = wv; t < 8; t += 4) {
        int bt = t & 1, ft = t >> 1;
        int s0 = __builtin_amdgcn_readfirstlane(S5[2 * n5]);
        int s1 = __builtin_amdgcn_readfirstlane(S5[2 * n5 + 1]);
        int f0 = ft * 16, bl = bt * 16;
        const unsigned short* a0 = W5b + (size_t)((f0 + c) * 3 + s0) * 64 + q * 8;
        const unsigned short* a1 = W5b + (size_t)((f0 + c) * 3 + s1) * 64 + q * 8;
        const unsigned short* bp0 = &L4o[((size_t)(0) * 32 + bl + c) * RPE + q * 8];
        const unsigned short* bp1 = &L4o[((size_t)(1) * 32 + bl + c) * RPE + q * 8];
        f32x4 acc0 = {0.f,0.f,0.f,0.f}, acc1 = {0.f,0.f,0.f,0.f};
        mfma_tile<64>(a0, a1, bp0, bp1, acc0, acc1);
        epilogue_store(X6 + ((size_t)n5 * 128 + b0 + bl + c) * 64 + f0 + q * 4,
                       acc0, acc1, B5, f0 + q * 4, s0, s1);
    }
}

// ============================================================================
// K3: L6+L7 fused. 128 blocks = (n7 of 16) x (b-16-tile of 8). 512 thr (8 waves).
// W from global Wb; L6 output staged in padded LDS (stride 136 -> 2-way only).
// X6 [64][128][64] -> X8 [16][128][256]
// ============================================================================
__global__ __launch_bounds__(512) void stage67_kernel(
    const unsigned short* __restrict__ X6,
    const unsigned short* __restrict__ W6b, const float* __restrict__ B6, const int* __restrict__ S6,
    const unsigned short* __restrict__ W7b, const float* __restrict__ B7, const int* __restrict__ S7,
    unsigned short* __restrict__ X8)
{
    constexpr int RPE = 136;                       // 128 + 8 pad
    __shared__ unsigned short L6o[2 * 16 * RPE];   // 8.7 KB

    const int tid  = threadIdx.x;
    const int lane = tid & 63;
    const int wv   = tid >> 6;                     // 0..7
    const int c = lane & 15, q = lane >> 4;
    const int n7 = blockIdx.x >> 3;                // 0..15
    const int b0 = (blockIdx.x & 7) * 16;

    // ---- L6 (CIN=64, CF=128): out pos 2n7+j (j=0,1), 8 f-tiles each ----
    for (int t = wv; t < 16; t += 8) {
        int j = t >> 3, ft = t & 7;
        int np = 2 * n7 + j;
        int s0 = __builtin_amdgcn_readfirstlane(S6[2 * np]);
        int s1 = __builtin_amdgcn_readfirstlane(S6[2 * np + 1]);
        int f0 = ft * 16;
        const unsigned short* a0 = W6b + (size_t)((f0 + c) * 3 + s0) * 64 + q * 8;
        const unsigned short* a1 = W6b + (size_t)((f0 + c) * 3 + s1) * 64 + q * 8;
        const unsigned short* bp0 = X6 + ((size_t)(2 * np) * 128 + b0 + c) * 64 + q * 8;
        const unsigned short* bp1 = X6 + ((size_t)(2 * np + 1) * 128 + b0 + c) * 64 + q * 8;
        f32x4 acc0 = {0.f,0.f,0.f,0.f}, acc1 = {0.f,0.f,0.f,0.f};
        mfma_tile<64>(a0, a1, bp0, bp1, acc0, acc1);
        epilogue_store(&L6o[((size_t)j * 16 + c) * RPE + f0 + q * 4],
                       acc0, acc1, B6, f0 + q * 4, s0, s1);
    }
    __syncthreads();

    // ---- L7 (CIN=128, CF=256): out pos n7, 16 f-tiles ----
    {
        int s0 = __builtin_amdgcn_readfirstlane(S7[2 * n7]);
        int s1 = __builtin_amdgcn_readfirstlane(S7[2 * n7 + 1]);
        for (int t = wv; t < 16; t += 8) {
            int f0 = t * 16;
            const unsigned short* a0 = W7b + (size_t)((f0 + c) * 3 + s0) * 128 + q * 8;
            const unsigned short* a1 = W7b + (size_t)((f0 + c) * 3 + s1) * 128 + q * 8;
            const unsigned short* bp0 = &L6o[((size_t)(0) * 16 + c) * RPE + q * 8];
            const unsigned short* bp1 = &L6o[((size_t)(1) * 16 + c) * RPE + q * 8];
            f32x4 acc0 = {0.f,0.f,0.f,0.f}, acc1 = {0.f,0.f,0.f,0.f};
            mfma_tile<128>(a0, a1, bp0, bp1, acc0, acc1);
            epilogue_store(X8 + ((size_t)n7 * 128 + b0 + c) * 256 + f0 + q * 4,
                           acc0, acc1, B7, f0 + q * 4, s0, s1);
        }
    }
}

// ============================================================================
// Flat MFMA layer (L8..L11): verified R9 body.
// ============================================================================
template<int CIN, int CF, int NP, int MW, int NW>
__global__ __launch_bounds__(256) void mfma_kernel(
    const unsigned short* __restrict__ Xin,
    const unsigned short* __restrict__ Wb,
    const float* __restrict__ bias,
    const int*   __restrict__ sel,
    unsigned short* __restrict__ Xout)
{
    constexpr int FT = CF / (16 * MW);
    constexpr int BT = 128 / (16 * NW);

    const int wid  = threadIdx.x >> 6;
    const int lane = threadIdx.x & 63;
    const int task = blockIdx.x * 4 + wid;
    const int bi = task % BT;
    const int fi = (task / BT) % FT;
    const int n  = task / (BT * FT);

    const int c = lane & 15;
    const int q = lane >> 4;
    const int s0 = __builtin_amdgcn_readfirstlane(sel[2 * n]);
    const int s1 = __builtin_amdgcn_readfirstlane(sel[2 * n + 1]);

    const int f0 = fi * 16 * MW;
    const int b0 = bi * 16 * NW;

    const unsigned short* ap[2][MW];
    const unsigned short* bp[2][NW];
#pragma unroll
    for (int p = 0; p < 2; ++p) {
        int s = p ? s1 : s0;
#pragma unroll
        for (int mi = 0; mi < MW; ++mi)
            ap[p][mi] = Wb + (size_t)((f0 + mi * 16 + c) * 3 + s) * CIN + q * 8;
#pragma unroll
        for (int ni = 0; ni < NW; ++ni)
            bp[p][ni] = Xin + ((size_t)(2 * n + p) * 128 + b0 + ni * 16 + c) * CIN + q * 8;
    }

    f32x4 acc[2][MW][NW];
#pragma unroll
    for (int p = 0; p < 2; ++p)
#pragma unroll
        for (int mi = 0; mi < MW; ++mi)
#pragma unroll
            for (int ni = 0; ni < NW; ++ni)
                acc[p][mi][ni] = (f32x4){0.f, 0.f, 0.f, 0.f};

#pragma unroll 2
    for (int k = 0; k < CIN; k += 32) {
        bf16x8 A[2][MW], B[2][NW];
#pragma unroll
        for (int p = 0; p < 2; ++p) {
#pragma unroll
            for (int mi = 0; mi < MW; ++mi)
                A[p][mi] = __builtin_bit_cast(bf16x8, *(const float4*)(const void*)(ap[p][mi] + k));
#pragma unroll
            for (int ni = 0; ni < NW; ++ni)
                B[p][ni] = __builtin_bit_cast(bf16x8, *(const float4*)(const void*)(bp[p][ni] + k));
        }
#pragma unroll
        for (int p = 0; p < 2; ++p)
#pragma unroll
            for (int mi = 0; mi < MW; ++mi)
#pragma unroll
                for (int ni = 0; ni < NW; ++ni)
                    acc[p][mi][ni] = __builtin_amdgcn_mfma_f32_16x16x32_bf16(
                        A[p][mi], B[p][ni], acc[p][mi][ni], 0, 0, 0);
    }

#pragma unroll
    for (int mi = 0; mi < MW; ++mi) {
        int fbase = f0 + mi * 16 + q * 4;
#pragma unroll
        for (int ni = 0; ni < NW; ++ni) {
            int b = b0 + ni * 16 + c;
            epilogue_store(Xout + ((size_t)n * 128 + b) * CF + fbase,
                           acc[0][mi][ni], acc[1][mi][ni], bias, fbase, s0, s1);
        }
    }
}

// ============================================================================
// FC head: h bf16 [128][1024]; out [128][16] fp32 log-softmax
// ============================================================================
__global__ __launch_bounds__(256) void fc_logsoftmax_kernel(
    const unsigned short* __restrict__ h, const float* __restrict__ fcW,
    const float* __restrict__ fcb, float* __restrict__ out)
{
    int b   = blockIdx.x;
    int tid = threadIdx.x;
    int k     = tid & 15;
    int chunk = tid >> 4;

    const float* __restrict__ wk = fcW + (size_t)k * 1024;
    const unsigned short* hb = h + (size_t)b * 1024;

    float partial = 0.0f;
    int j0 = chunk * 64;
#pragma unroll 8
    for (int j = 0; j < 64; ++j)
        partial = fmaf(bf2f(hb[j0 + j]), wk[j0 + j], partial);

    __shared__ float red[16][17];
    red[chunk][k] = partial;
    __syncthreads();

    __shared__ float logits[16];
    if (tid < 16) {
        float s = fcb[tid];
#pragma unroll
        for (int c = 0; c < 16; ++c) s += red[c][tid];
        logits[tid] = s;
    }
    __syncthreads();

    if (tid < 16) {
        float mx = -INFINITY;
#pragma unroll
        for (int kk = 0; kk < 16; ++kk) mx = fmaxf(mx, logits[kk]);
        float se = 0.0f;
#pragma unroll
        for (int kk = 0; kk < 16; ++kk) se += expf(logits[kk] - mx);
        out[b * 16 + tid] = logits[tid] - mx - logf(se);
    }
}

// ============================================================================
extern "C" void kernel_launch(void* const* d_in, const int* in_sizes, int n_in,
                              void* d_out, int out_size, void* d_ws, size_t ws_size,
                              hipStream_t stream)
{
#define WL(i) (const float*)d_in[1 + 3 * (i)]
#define BL(i) (const float*)d_in[2 + 3 * (i)]
#define SL(i) (const int*)  d_in[3 + 3 * (i)]

    unsigned short* bufA = (unsigned short*)d_ws;          // 4 MB
    unsigned short* bufB = bufA + 2u * 1024u * 1024u;      // 4 MB
    unsigned short* Wb   = bufB + 2u * 1024u * 1024u;      // packed W3..W11 bf16

    const int o6 = 30720, o7 = 55296, o8 = 153600,
              o9 = 546816, o10 = 1333248, o11 = 2119680;

    // ---- K1: pack(W3..W11) || L1+L2 -> X3 (bufA) ----
    K1Params P;
    P.x = (const float*)d_in[0];
    P.W1 = WL(0); P.B1 = BL(0); P.S1 = SL(0);
    P.W2 = WL(1); P.B2 = BL(1); P.S2 = SL(1);
    for (int i = 0; i < 9; ++i) P.Wsrc[i] = WL(2 + i);
    P.Wb = Wb; P.X3 = bufA;
    k1_kernel<<<256, 256, 0, stream>>>(P);

    // ---- K2: L3+L4+L5 -> X6 (bufB) ----
    stage2_kernel<<<256, 256, 0, stream>>>(bufA, Wb,
        BL(2), SL(2), BL(3), SL(3), BL(4), SL(4), bufB);

    // ---- K3: L6+L7 -> X8 (bufA) ----
    stage67_kernel<<<128, 512, 0, stream>>>(bufB,
        Wb + o6, BL(5), SL(5), Wb + o7, BL(6), SL(6), bufA);

    // ---- K4..K7: flat MFMA layers (NW=1 on tail for 2x waves) ----
    mfma_kernel<256, 512, 8, 2, 2><<<128, 256, 0, stream>>>(bufA, Wb + o8,  BL(7),  SL(7),  bufB);
    mfma_kernel<512, 512, 4, 1, 1><<<256, 256, 0, stream>>>(bufB, Wb + o9,  BL(8),  SL(8),  bufA);
    mfma_kernel<512, 512, 2, 1, 1><<<128, 256, 0, stream>>>(bufA, Wb + o10, BL(9),  SL(9),  bufB);
    mfma_kernel<512, 1024, 1, 1, 1><<<128, 256, 0, stream>>>(bufB, Wb + o11, BL(10), SL(10), bufA);

    // ---- K8: FC ----
    fc_logsoftmax_kernel<<<128, 256, 0, stream>>>(bufA, (const float*)d_in[34], (const float*)d_in[35], (float*)d_out);

#undef WL
#undef BL
#undef SL
}